// Round 12
// baseline (396.156 us; speedup 1.0000x reference)
//
#include <hip/hip_runtime.h>
#include <hip/hip_cooperative_groups.h>
#include <stdint.h>

namespace cg = cooperative_groups;

#define N_V 100000
#define N_E 200000
#define NNZ 800000
#define D_IN 14
#define H 128

#define RSH 8             // row bucket = 256 vertices
#define CSH 9             // col bucket = 512 edges
#define NB 391            // bucket count (R and C) and bin chunk count
#define CAPR 3072
#define CAPC 3072
#define VMASK 0x3FFFFu
#define GRID 256
#define THR 512

struct Pk {
  const int* rows; const int* cols;
  const float* X; const float* W0; const float* b0;
  const float* Wl0; const float* bl0; const float* Wl1; const float* bl1;
  const float* Wo0; const float* bo0; const float* Wo1; const float* bo1;
  float* out;
  int* cntR; int* cntC;
  float* qsum; float* sumn2; float* sumzn; float* tg;
  float* rdegf; float* invdg; float* Wv; float* Sv; float* WvD;
  float2* wn; float* zM; float* W0f; float* b0f;
  unsigned* binnedR; unsigned* binnedC;
};

#define SHFL6(v) do { \
  v += __shfl_xor(v, 1);  v += __shfl_xor(v, 2);  v += __shfl_xor(v, 4); \
  v += __shfl_xor(v, 8);  v += __shfl_xor(v, 16); v += __shfl_xor(v, 32); } while (0)

__global__ __launch_bounds__(THR) void k_mega(Pk p) {
  cg::grid_group grid = cg::this_grid();
  __shared__ __align__(16) char smem[20480];
  int t = threadIdx.x;

  // ---- P(-1): zero small state ----
  if (blockIdx.x == 0) {
    if (t < NB) { p.cntR[t] = 0; p.cntC[t] = 0; }
    if (t >= 448) p.tg[t - 448] = 0.f;
    if (t == 440) *p.qsum = 0.f;
    if (t == 441) *p.sumn2 = 0.f;
    if (t == 442) *p.sumzn = 0.f;
  }
  grid.sync();

  // ---- P0: bin both directions, 2048 records per chunk ----
  {
    int* bcnt = (int*)smem;
    int* bsc  = (int*)(smem + 2048);
    int* bex  = (int*)(smem + 4096);
    int* gb   = (int*)(smem + 6144);
    unsigned* recs = (unsigned*)(smem + 8192);
    unsigned short* bid = (unsigned short*)(smem + 16384);
    for (int ck = blockIdx.x; ck < NB; ck += GRID) {
      int base = ck * 2048;
      int r_[4], c_[4], lp[4], bb[4];
#pragma unroll
      for (int u = 0; u < 4; u++) {
        int i = base + u * 512 + t;
        if (i < NNZ) { r_[u] = p.rows[i]; c_[u] = p.cols[i]; } else r_[u] = -1;
      }
      // phase R: key=row, val=col
      bcnt[t] = 0;
      __syncthreads();
#pragma unroll
      for (int u = 0; u < 4; u++) {
        if (r_[u] >= 0) { int b2 = r_[u] >> RSH; bb[u] = b2; lp[u] = atomicAdd(&bcnt[b2], 1); }
        else bb[u] = -1;
      }
      __syncthreads();
      bsc[t] = bcnt[t];
      __syncthreads();
      for (int o = 1; o < 512; o <<= 1) {
        int x = (t >= o) ? bsc[t - o] : 0;
        __syncthreads();
        bsc[t] += x;
        __syncthreads();
      }
      bex[t] = bsc[t] - bcnt[t];
      __syncthreads();
#pragma unroll
      for (int u = 0; u < 4; u++) {
        if (bb[u] >= 0) {
          int pp = bex[bb[u]] + lp[u];
          recs[pp] = ((unsigned)(r_[u] & 255) << 18) | (unsigned)c_[u];
          bid[pp] = (unsigned short)bb[u];
        }
      }
      if (t < NB && bcnt[t] > 0) gb[t] = t * CAPR + atomicAdd(&p.cntR[t], bcnt[t]);
      __syncthreads();
      int total = bsc[511];
      for (int pp = t; pp < total; pp += 512) {
        int b2 = bid[pp];
        p.binnedR[gb[b2] + (pp - bex[b2])] = recs[pp];
      }
      __syncthreads();
      // phase C: key=col, val=row
      bcnt[t] = 0;
      __syncthreads();
#pragma unroll
      for (int u = 0; u < 4; u++) {
        if (r_[u] >= 0) { int b2 = c_[u] >> CSH; bb[u] = b2; lp[u] = atomicAdd(&bcnt[b2], 1); }
        else bb[u] = -1;
      }
      __syncthreads();
      bsc[t] = bcnt[t];
      __syncthreads();
      for (int o = 1; o < 512; o <<= 1) {
        int x = (t >= o) ? bsc[t - o] : 0;
        __syncthreads();
        bsc[t] += x;
        __syncthreads();
      }
      bex[t] = bsc[t] - bcnt[t];
      __syncthreads();
#pragma unroll
      for (int u = 0; u < 4; u++) {
        if (bb[u] >= 0) {
          int pp = bex[bb[u]] + lp[u];
          recs[pp] = ((unsigned)(c_[u] & 511) << 18) | (unsigned)r_[u];
          bid[pp] = (unsigned short)bb[u];
        }
      }
      if (t < NB && bcnt[t] > 0) gb[t] = t * CAPC + atomicAdd(&p.cntC[t], bcnt[t]);
      __syncthreads();
      total = bsc[511];
      for (int pp = t; pp < total; pp += 512) {
        int b2 = bid[pp];
        p.binnedC[gb[b2] + (pp - bex[b2])] = recs[pp];
      }
      __syncthreads();
    }
  }
  grid.sync();

  // ---- P1: fhist (vertex degree) + fusew riders ----
  {
    int* d_l = (int*)smem;
    for (int bk = blockIdx.x; bk < NB; bk += GRID) {
      if (t < 256) d_l[t] = 0;
      __syncthreads();
      int cnt = p.cntR[bk];
      const unsigned* rec = p.binnedR + (size_t)bk * CAPR;
      int pp = t;
      for (; pp + 1536 < cnt; pp += 2048) {
        unsigned a0 = rec[pp], a1 = rec[pp + 512], a2 = rec[pp + 1024], a3 = rec[pp + 1536];
        atomicAdd(&d_l[a0 >> 18], 1); atomicAdd(&d_l[a1 >> 18], 1);
        atomicAdd(&d_l[a2 >> 18], 1); atomicAdd(&d_l[a3 >> 18], 1);
      }
      for (; pp < cnt; pp += 512) atomicAdd(&d_l[rec[pp] >> 18], 1);
      __syncthreads();
      if (t < 256) {
        int v = (bk << RSH) + t;
        if (v < N_V) {
          int s = d_l[t];
          p.rdegf[v] = (float)s;
          p.invdg[v] = 1.f / (float)(s > 0 ? s : 1);
        }
      }
      __syncthreads();
    }
    int d = blockIdx.x;
    if (d < D_IN + 1) {     // fusew: W0f = W0@Wl0 ; b0f = b0@Wl0 + bl0
      float* fw = (float*)(smem + 4096);
      int n = t & 127, seg = t >> 7;
      float part = 0.f;
      if (d < D_IN) {
        for (int k = seg * 32; k < seg * 32 + 32; k++) part += p.W0[d * H + k] * p.Wl0[k * H + n];
      } else {
        for (int k = seg * 32; k < seg * 32 + 32; k++) part += p.b0[k] * p.Wl0[k * H + n];
      }
      fw[seg * 128 + n] = part;
      __syncthreads();
      if (t < 128) {
        float s = fw[t] + fw[128 + t] + fw[256 + t] + fw[384 + t];
        if (d < D_IN) p.W0f[d * H + t] = s;
        else p.b0f[t] = s + p.bl0[t];
      }
    }
  }
  grid.sync();

  // ---- P2: fA — edge histogram + w_j; wn=(w,n); qsum += w*n; sumn2 += n^2 ----
  {
    int* n_l = (int*)smem;
    float* w_l = (float*)(smem + 2048);
    float* red = (float*)(smem + 4096);
    float qacc = 0.f, n2acc = 0.f;
    for (int bk = blockIdx.x; bk < NB; bk += GRID) {
      n_l[t] = 0; w_l[t] = 0.f;
      __syncthreads();
      int cnt = p.cntC[bk];
      const unsigned* rec = p.binnedC + (size_t)bk * CAPC;
      int pp = t;
      for (; pp + 1536 < cnt; pp += 2048) {
        unsigned a0 = rec[pp], a1 = rec[pp + 512], a2 = rec[pp + 1024], a3 = rec[pp + 1536];
        float i0 = p.invdg[a0 & VMASK], i1 = p.invdg[a1 & VMASK];
        float i2 = p.invdg[a2 & VMASK], i3 = p.invdg[a3 & VMASK];
        atomicAdd(&n_l[a0 >> 18], 1); atomicAdd(&w_l[a0 >> 18], i0);
        atomicAdd(&n_l[a1 >> 18], 1); atomicAdd(&w_l[a1 >> 18], i1);
        atomicAdd(&n_l[a2 >> 18], 1); atomicAdd(&w_l[a2 >> 18], i2);
        atomicAdd(&n_l[a3 >> 18], 1); atomicAdd(&w_l[a3 >> 18], i3);
      }
      for (; pp < cnt; pp += 512) {
        unsigned a0 = rec[pp];
        atomicAdd(&n_l[a0 >> 18], 1);
        atomicAdd(&w_l[a0 >> 18], p.invdg[a0 & VMASK]);
      }
      __syncthreads();
      int e = (bk << CSH) + t;
      if (e < N_E) {
        float n = (float)n_l[t], wf = w_l[t];
        p.wn[e] = make_float2(wf, n);
        qacc += wf * n;
        n2acc += n * n;
      }
      __syncthreads();
    }
    red[t] = qacc;
    __syncthreads();
    for (int o = 256; o > 0; o >>= 1) { if (t < o) red[t] += red[t + o]; __syncthreads(); }
    if (t == 0) atomicAdd(p.qsum, red[0]);
    __syncthreads();
    red[t] = n2acc;
    __syncthreads();
    for (int o = 256; o > 0; o >>= 1) { if (t < o) red[t] += red[t + o]; __syncthreads(); }
    if (t == 0) atomicAdd(p.sumn2, red[0]);
  }
  grid.sync();

  // ---- P3: fB — Wv[r]+=w[c], Sv[r]+=n[c]; WvD = Wv*invdeg ----
  {
    float* W_l = (float*)smem;
    float* S_l = (float*)(smem + 1024);
    for (int bk = blockIdx.x; bk < NB; bk += GRID) {
      if (t < 256) { W_l[t] = 0.f; S_l[t] = 0.f; }
      __syncthreads();
      int cnt = p.cntR[bk];
      const unsigned* rec = p.binnedR + (size_t)bk * CAPR;
      int pp = t;
      for (; pp + 1536 < cnt; pp += 2048) {
        unsigned a0 = rec[pp], a1 = rec[pp + 512], a2 = rec[pp + 1024], a3 = rec[pp + 1536];
        float2 w0 = p.wn[a0 & VMASK], w1 = p.wn[a1 & VMASK];
        float2 w2 = p.wn[a2 & VMASK], w3 = p.wn[a3 & VMASK];
        atomicAdd(&W_l[a0 >> 18], w0.x); atomicAdd(&S_l[a0 >> 18], w0.y);
        atomicAdd(&W_l[a1 >> 18], w1.x); atomicAdd(&S_l[a1 >> 18], w1.y);
        atomicAdd(&W_l[a2 >> 18], w2.x); atomicAdd(&S_l[a2 >> 18], w2.y);
        atomicAdd(&W_l[a3 >> 18], w3.x); atomicAdd(&S_l[a3 >> 18], w3.y);
      }
      for (; pp < cnt; pp += 512) {
        unsigned a0 = rec[pp];
        float2 w0 = p.wn[a0 & VMASK];
        atomicAdd(&W_l[a0 >> 18], w0.x); atomicAdd(&S_l[a0 >> 18], w0.y);
      }
      __syncthreads();
      if (t < 256) {
        int v = (bk << RSH) + t;
        if (v < N_V) {
          float W = W_l[t];
          p.Wv[v] = W; p.Sv[v] = S_l[t]; p.WvD[v] = W * p.invdg[v];
        }
      }
      __syncthreads();
    }
  }
  grid.sync();

  // ---- P4: fC — z[c] += WvD[r] -> zM; sumzn += z*n ----
  {
    float* z_l = (float*)smem;
    float* red = (float*)(smem + 2048);
    float znacc = 0.f;
    for (int bk = blockIdx.x; bk < NB; bk += GRID) {
      z_l[t] = 0.f;
      __syncthreads();
      int cnt = p.cntC[bk];
      const unsigned* rec = p.binnedC + (size_t)bk * CAPC;
      int pp = t;
      for (; pp + 1536 < cnt; pp += 2048) {
        unsigned a0 = rec[pp], a1 = rec[pp + 512], a2 = rec[pp + 1024], a3 = rec[pp + 1536];
        float v0 = p.WvD[a0 & VMASK], v1 = p.WvD[a1 & VMASK];
        float v2 = p.WvD[a2 & VMASK], v3 = p.WvD[a3 & VMASK];
        atomicAdd(&z_l[a0 >> 18], v0); atomicAdd(&z_l[a1 >> 18], v1);
        atomicAdd(&z_l[a2 >> 18], v2); atomicAdd(&z_l[a3 >> 18], v3);
      }
      for (; pp < cnt; pp += 512) {
        unsigned a0 = rec[pp];
        atomicAdd(&z_l[a0 >> 18], p.WvD[a0 & VMASK]);
      }
      __syncthreads();
      int e = (bk << CSH) + t;
      if (e < N_E) {
        float z = z_l[t];
        p.zM[e] = z;
        znacc += z * p.wn[e].y;
      }
      __syncthreads();
    }
    red[t] = znacc;
    __syncthreads();
    for (int o = 256; o > 0; o >>= 1) { if (t < o) red[t] += red[t + o]; __syncthreads(); }
    if (t == 0) atomicAdd(p.sumzn, red[0]);
  }
  grid.sync();

  // ---- P5: fD — Z2 in LDS + weighted X colsums -> tg[64] ----
  {
    float* Z_l = (float*)smem;
    float* tl = (float*)(smem + 2048);
    if (t < 64) tl[t] = 0.f;
    __syncthreads();
    for (int bk = blockIdx.x; bk < NB; bk += GRID) {
      if (t < 256) Z_l[t] = 0.f;
      __syncthreads();
      int cnt = p.cntR[bk];
      const unsigned* rec = p.binnedR + (size_t)bk * CAPR;
      int pp = t;
      for (; pp + 1536 < cnt; pp += 2048) {
        unsigned a0 = rec[pp], a1 = rec[pp + 512], a2 = rec[pp + 1024], a3 = rec[pp + 1536];
        float v0 = p.zM[a0 & VMASK], v1 = p.zM[a1 & VMASK];
        float v2 = p.zM[a2 & VMASK], v3 = p.zM[a3 & VMASK];
        atomicAdd(&Z_l[a0 >> 18], v0); atomicAdd(&Z_l[a1 >> 18], v1);
        atomicAdd(&Z_l[a2 >> 18], v2); atomicAdd(&Z_l[a3 >> 18], v3);
      }
      for (; pp < cnt; pp += 512) {
        unsigned a0 = rec[pp];
        atomicAdd(&Z_l[a0 >> 18], p.zM[a0 & VMASK]);
      }
      __syncthreads();
      if (t < 256) {
        int lane = t & 63;
        int v = (bk << RSH) + t;
        bool ok = v < N_V;
        float g0 = 0.f, g1 = 0.f, g2 = 0.f, g3 = 0.f;
        if (ok) {
          float W = p.Wv[v];
          g0 = 1.f; g1 = W;
          g2 = p.rdegf[v] + p.Sv[v];
          g3 = W + Z_l[t];
        }
        const float2* X2 = (const float2*)p.X;
#pragma unroll
        for (int q = 0; q < 7; q++) {
          float2 xp = ok ? X2[(size_t)v * 7 + q] : make_float2(0.f, 0.f);
#pragma unroll
          for (int hh = 0; hh < 2; hh++) {
            float xv = hh ? xp.y : xp.x;
            int d = 2 * q + hh;
            float v0 = xv * g0, v1 = xv * g1, v2 = xv * g2, v3 = xv * g3;
            SHFL6(v0); SHFL6(v1); SHFL6(v2); SHFL6(v3);
            if (lane == 0) {
              atomicAdd(&tl[d], v0);
              atomicAdd(&tl[16 + d], v1);
              atomicAdd(&tl[32 + d], v2);
              atomicAdd(&tl[48 + d], v3);
            }
          }
        }
      }
      __syncthreads();
    }
    if (t < 64) atomicAdd(&p.tg[t], tl[t]);
  }
  grid.sync();

  // ---- P6: final (block 0) ----
  if (blockIdx.x == 0) {
    float* cs = (float*)smem;
    float* red = (float*)(smem + 2048);
    float Q = p.qsum[0];
    if (t < 128) {
      float c0 = 0.f, c1 = 0.f, c2 = 0.f, c3 = 0.f;
      for (int d = 0; d < D_IN; d++) {
        float w = p.W0f[d * H + t];
        c0 += p.tg[d] * w;
        c1 += p.tg[16 + d] * w;
        c2 += p.tg[32 + d] * w;
        c3 += p.tg[48 + d] * w;
      }
      float bv = p.b0f[t];
      cs[t]       = c0 + (float)N_V * bv;
      cs[128 + t] = c1 + Q * bv;
      cs[256 + t] = c2 + ((float)NNZ + p.sumn2[0]) * bv;
      cs[384 + t] = c3 + (Q + p.sumzn[0]) * bv;
    }
    __syncthreads();
    if (t < 128) {
      float sx = 0.f, se = 0.f;
      for (int k = 0; k < H; k++) {
        float wv = p.Wl1[k * H + t];
        float csx = cs[k] + cs[128 + k];     // colsum(a2) = colsum(h1) + sum w_k e1_k
        sx += (csx + cs[384 + k]) * wv;
        se += cs[256 + k] * wv;
      }
      sx += ((float)N_V + Q) * p.bl1[t];
      se += (float)NNZ * p.bl1[t];
      red[t] = sx * (1.f / (float)N_V) * p.Wo0[t] + se * (1.f / (float)N_E) * p.Wo1[t];
    }
    __syncthreads();
    for (int o = 64; o > 0; o >>= 1) {
      if (t < 128 && t < o) red[t] += red[t + o];
      __syncthreads();
    }
    if (t == 0) p.out[0] = red[0] + p.bo0[0] + p.bo1[0];
  }
}

extern "C" void kernel_launch(void* const* d_in, const int* in_sizes, int n_in,
                              void* d_out, int out_size, void* d_ws, size_t ws_size,
                              hipStream_t stream) {
  char* ws = (char*)d_ws;
  Pk p;
  p.rows = (const int*)d_in[2];
  p.cols = (const int*)d_in[3];
  p.X    = (const float*)d_in[0];
  p.W0   = (const float*)d_in[4];
  p.b0   = (const float*)d_in[5];
  p.Wl0  = (const float*)d_in[8];
  p.bl0  = (const float*)d_in[9];
  p.Wl1  = (const float*)d_in[10];
  p.bl1  = (const float*)d_in[11];
  p.Wo0  = (const float*)d_in[12];
  p.bo0  = (const float*)d_in[13];
  p.Wo1  = (const float*)d_in[14];
  p.bo1  = (const float*)d_in[15];
  p.out  = (float*)d_out;

  p.cntR  = (int*)(ws + 0);                  // 391 ints (pad 2048)
  p.cntC  = (int*)(ws + 2048);               // 391 ints (pad 2048)
  p.qsum  = (float*)(ws + 4096);
  p.sumn2 = (float*)(ws + 4100);
  p.sumzn = (float*)(ws + 4104);
  p.tg    = (float*)(ws + 4352);             // 64 floats
  p.rdegf = (float*)(ws + 8192);             // 400,000
  p.invdg = (float*)(ws + 408192);           // 400,000
  p.Wv    = (float*)(ws + 808192);           // 400,000
  p.Sv    = (float*)(ws + 1208192);          // 400,000
  p.WvD   = (float*)(ws + 1608192);          // 400,000
  p.wn    = (float2*)(ws + 2008192);         // 1,600,000
  p.zM    = (float*)(ws + 3608192);          // 800,000
  p.W0f   = (float*)(ws + 4408192);          // 7,168
  p.b0f   = (float*)(ws + 4415360);          // 512
  p.binnedR = (unsigned*)(ws + 4415872);     // 391*3072*4 = 4,804,608
  p.binnedC = (unsigned*)(ws + 9220480);     // 4,804,608
  // total: 14,025,088 B

  void* args[] = { &p };
  hipLaunchCooperativeKernel(reinterpret_cast<void*>(k_mega), dim3(GRID), dim3(THR),
                             args, 0, stream);
}

// Round 13
// 182.490 us; speedup vs baseline: 2.1708x; 2.1708x over previous
//
#include <hip/hip_runtime.h>
#include <stdint.h>

#define N_V 100000
#define N_E 200000
#define NNZ 800000
#define D_IN 14
#define H 128

#define RSH 8             // row bucket = 256 vertices
#define CSH 9             // col bucket = 512 edges
#define NB_R 391          // ceil(N_V/256)
#define NB_C 391          // ceil(N_E/512)
#define NBIN 196          // ceil(NNZ/4096) bin chunks
#define CAPR 3072
#define CAPC 3072
#define VMASK 0x3FFFFu

// ---------------- merged bin (both directions, 4096 rec/block) + fusew riders ----------------
__global__ __launch_bounds__(1024) void k_bin2(const int* __restrict__ rows, const int* __restrict__ cols,
                                               const float* __restrict__ W0, const float* __restrict__ b0,
                                               const float* __restrict__ Wl0, const float* __restrict__ bl0,
                                               float* __restrict__ W0f, float* __restrict__ b0f,
                                               unsigned* __restrict__ binnedR, int* __restrict__ cntR,
                                               unsigned* __restrict__ binnedC, int* __restrict__ cntC) {
  int t = threadIdx.x;
  if (blockIdx.x >= NBIN) {         // fusew rider: W0f = W0@Wl0, b0f = b0@Wl0 + bl0
    if (t < 128) {
      int n = t, d = blockIdx.x - NBIN;
      if (d < D_IN) {
        float acc = 0.f;
        for (int k = 0; k < H; k++) acc += W0[d * H + k] * Wl0[k * H + n];
        W0f[d * H + n] = acc;
      } else {
        float accb = bl0[n];
        for (int k = 0; k < H; k++) accb += b0[k] * Wl0[k * H + n];
        b0f[n] = accb;
      }
    }
    return;
  }
  __shared__ int bcnt[512], bsc[512], bex[512], gb[512];
  __shared__ unsigned recs[4096];
  __shared__ unsigned short bid[4096];
  int r_[4], c_[4], lp[4], bb[4];
  int base = blockIdx.x * 4096;
#pragma unroll
  for (int u = 0; u < 4; u++) {
    int i = base + u * 1024 + t;
    if (i < NNZ) { r_[u] = rows[i]; c_[u] = cols[i]; } else r_[u] = -1;
  }
  // ---- phase R: key=row, val=col ----
  if (t < 512) bcnt[t] = 0;
  __syncthreads();
#pragma unroll
  for (int u = 0; u < 4; u++) {
    if (r_[u] >= 0) { int b = r_[u] >> RSH; bb[u] = b; lp[u] = atomicAdd(&bcnt[b], 1); }
    else bb[u] = -1;
  }
  __syncthreads();
  if (t < 512) bsc[t] = bcnt[t];
  __syncthreads();
  for (int o = 1; o < 512; o <<= 1) {
    int x = (t < 512 && t >= o) ? bsc[t - o] : 0;
    __syncthreads();
    if (t < 512) bsc[t] += x;
    __syncthreads();
  }
  if (t < 512) bex[t] = bsc[t] - bcnt[t];
  __syncthreads();
#pragma unroll
  for (int u = 0; u < 4; u++) {
    if (bb[u] >= 0) {
      int p = bex[bb[u]] + lp[u];
      recs[p] = ((unsigned)(r_[u] & 255) << 18) | (unsigned)c_[u];
      bid[p] = (unsigned short)bb[u];
    }
  }
  if (t < NB_R && bcnt[t] > 0) gb[t] = t * CAPR + atomicAdd(&cntR[t], bcnt[t]);
  __syncthreads();
  int total = bsc[511];
  for (int p = t; p < total; p += 1024) {
    int b = bid[p];
    binnedR[gb[b] + (p - bex[b])] = recs[p];
  }
  __syncthreads();
  // ---- phase C: key=col, val=row ----
  if (t < 512) bcnt[t] = 0;
  __syncthreads();
#pragma unroll
  for (int u = 0; u < 4; u++) {
    if (r_[u] >= 0) { int b = c_[u] >> CSH; bb[u] = b; lp[u] = atomicAdd(&bcnt[b], 1); }
    else bb[u] = -1;
  }
  __syncthreads();
  if (t < 512) bsc[t] = bcnt[t];
  __syncthreads();
  for (int o = 1; o < 512; o <<= 1) {
    int x = (t < 512 && t >= o) ? bsc[t - o] : 0;
    __syncthreads();
    if (t < 512) bsc[t] += x;
    __syncthreads();
  }
  if (t < 512) bex[t] = bsc[t] - bcnt[t];
  __syncthreads();
#pragma unroll
  for (int u = 0; u < 4; u++) {
    if (bb[u] >= 0) {
      int p = bex[bb[u]] + lp[u];
      recs[p] = ((unsigned)(c_[u] & 511) << 18) | (unsigned)r_[u];
      bid[p] = (unsigned short)bb[u];
    }
  }
  if (t < NB_C && bcnt[t] > 0) gb[t] = t * CAPC + atomicAdd(&cntC[t], bcnt[t]);
  __syncthreads();
  total = bsc[511];
  for (int p = t; p < total; p += 1024) {
    int b = bid[p];
    binnedC[gb[b] + (p - bex[b])] = recs[p];
  }
}

// ---------------- fine: vertex degree -> rdegf, invdg ----------------
__global__ __launch_bounds__(512) void k_fhist(const unsigned* __restrict__ binnedR, const int* __restrict__ cntR,
                                               float* __restrict__ rdegf, float* __restrict__ invdg) {
  __shared__ int d_l[256];
  int t = threadIdx.x, b = blockIdx.x;
  if (t < 256) d_l[t] = 0;
  __syncthreads();
  int cnt = cntR[b];
  const unsigned* rec = binnedR + (size_t)b * CAPR;
  int p = t;
  for (; p + 1536 < cnt; p += 2048) {
    unsigned a0 = rec[p], a1 = rec[p + 512], a2 = rec[p + 1024], a3 = rec[p + 1536];
    atomicAdd(&d_l[a0 >> 18], 1); atomicAdd(&d_l[a1 >> 18], 1);
    atomicAdd(&d_l[a2 >> 18], 1); atomicAdd(&d_l[a3 >> 18], 1);
  }
  for (; p < cnt; p += 512) atomicAdd(&d_l[rec[p] >> 18], 1);
  __syncthreads();
  if (t < 256) {
    int v = (b << RSH) + t;
    if (v < N_V) {
      int s = d_l[t];
      rdegf[v] = (float)s;
      invdg[v] = 1.f / (float)(s > 0 ? s : 1);
    }
  }
}

// ---------------- fine A: edge histogram + w_j; wn=(w,n); qsum += w*n; sumn2 += n^2 ----------------
__global__ __launch_bounds__(512) void k_fA(const unsigned* __restrict__ binnedC, const int* __restrict__ cntC,
                                            const float* __restrict__ invdg,
                                            float2* __restrict__ wn, float* __restrict__ qsum,
                                            float* __restrict__ sumn2) {
  __shared__ int n_l[512];
  __shared__ float w_l[512];
  __shared__ float red[512];
  int t = threadIdx.x, b = blockIdx.x;
  n_l[t] = 0; w_l[t] = 0.f;
  __syncthreads();
  int cnt = cntC[b];
  const unsigned* rec = binnedC + (size_t)b * CAPC;
  int p = t;
  for (; p + 1536 < cnt; p += 2048) {
    unsigned a0 = rec[p], a1 = rec[p + 512], a2 = rec[p + 1024], a3 = rec[p + 1536];
    float i0 = invdg[a0 & VMASK], i1 = invdg[a1 & VMASK];
    float i2 = invdg[a2 & VMASK], i3 = invdg[a3 & VMASK];
    atomicAdd(&n_l[a0 >> 18], 1); atomicAdd(&w_l[a0 >> 18], i0);
    atomicAdd(&n_l[a1 >> 18], 1); atomicAdd(&w_l[a1 >> 18], i1);
    atomicAdd(&n_l[a2 >> 18], 1); atomicAdd(&w_l[a2 >> 18], i2);
    atomicAdd(&n_l[a3 >> 18], 1); atomicAdd(&w_l[a3 >> 18], i3);
  }
  for (; p < cnt; p += 512) {
    unsigned a0 = rec[p];
    atomicAdd(&n_l[a0 >> 18], 1);
    atomicAdd(&w_l[a0 >> 18], invdg[a0 & VMASK]);
  }
  __syncthreads();
  float q = 0.f, n2 = 0.f;
  int e = (b << CSH) + t;
  if (e < N_E) {
    float n = (float)n_l[t], wf = w_l[t];
    wn[e] = make_float2(wf, n);
    q = wf * n;
    n2 = n * n;
  }
  red[t] = q;
  __syncthreads();
  for (int o = 256; o > 0; o >>= 1) {
    if (t < o) red[t] += red[t + o];
    __syncthreads();
  }
  if (t == 0) atomicAdd(qsum, red[0]);
  __syncthreads();
  red[t] = n2;
  __syncthreads();
  for (int o = 256; o > 0; o >>= 1) {
    if (t < o) red[t] += red[t + o];
    __syncthreads();
  }
  if (t == 0) atomicAdd(sumn2, red[0]);
}

// ---------------- fine B: Wv[r]+=w[c], Sv[r]+=n[c]; WvD = Wv*invdeg ----------------
__global__ __launch_bounds__(512) void k_fB(const unsigned* __restrict__ binnedR, const int* __restrict__ cntR,
                                            const float2* __restrict__ wn, const float* __restrict__ invdg,
                                            float* __restrict__ Wv, float* __restrict__ Sv,
                                            float* __restrict__ WvD) {
  __shared__ float W_l[256], S_l[256];
  int t = threadIdx.x, b = blockIdx.x;
  if (t < 256) { W_l[t] = 0.f; S_l[t] = 0.f; }
  __syncthreads();
  int cnt = cntR[b];
  const unsigned* rec = binnedR + (size_t)b * CAPR;
  int p = t;
  for (; p + 1536 < cnt; p += 2048) {
    unsigned a0 = rec[p], a1 = rec[p + 512], a2 = rec[p + 1024], a3 = rec[p + 1536];
    float2 w0 = wn[a0 & VMASK], w1 = wn[a1 & VMASK], w2 = wn[a2 & VMASK], w3 = wn[a3 & VMASK];
    atomicAdd(&W_l[a0 >> 18], w0.x); atomicAdd(&S_l[a0 >> 18], w0.y);
    atomicAdd(&W_l[a1 >> 18], w1.x); atomicAdd(&S_l[a1 >> 18], w1.y);
    atomicAdd(&W_l[a2 >> 18], w2.x); atomicAdd(&S_l[a2 >> 18], w2.y);
    atomicAdd(&W_l[a3 >> 18], w3.x); atomicAdd(&S_l[a3 >> 18], w3.y);
  }
  for (; p < cnt; p += 512) {
    unsigned a0 = rec[p];
    float2 w0 = wn[a0 & VMASK];
    atomicAdd(&W_l[a0 >> 18], w0.x); atomicAdd(&S_l[a0 >> 18], w0.y);
  }
  __syncthreads();
  if (t < 256) {
    int v = (b << RSH) + t;
    if (v < N_V) {
      float W = W_l[t];
      Wv[v] = W; Sv[v] = S_l[t]; WvD[v] = W * invdg[v];
    }
  }
}

// ---------------- fine C: z[c] += WvD[r] -> zM; sumzn += z*n ----------------
__global__ __launch_bounds__(512) void k_fC(const unsigned* __restrict__ binnedC, const int* __restrict__ cntC,
                                            const float* __restrict__ WvD, const float2* __restrict__ wn,
                                            float* __restrict__ zM, float* __restrict__ sumzn) {
  __shared__ float z_l[512];
  __shared__ float red[512];
  int t = threadIdx.x, b = blockIdx.x;
  z_l[t] = 0.f;
  __syncthreads();
  int cnt = cntC[b];
  const unsigned* rec = binnedC + (size_t)b * CAPC;
  int p = t;
  for (; p + 1536 < cnt; p += 2048) {
    unsigned a0 = rec[p], a1 = rec[p + 512], a2 = rec[p + 1024], a3 = rec[p + 1536];
    float v0 = WvD[a0 & VMASK], v1 = WvD[a1 & VMASK], v2 = WvD[a2 & VMASK], v3 = WvD[a3 & VMASK];
    atomicAdd(&z_l[a0 >> 18], v0); atomicAdd(&z_l[a1 >> 18], v1);
    atomicAdd(&z_l[a2 >> 18], v2); atomicAdd(&z_l[a3 >> 18], v3);
  }
  for (; p < cnt; p += 512) {
    unsigned a0 = rec[p];
    atomicAdd(&z_l[a0 >> 18], WvD[a0 & VMASK]);
  }
  __syncthreads();
  float q = 0.f;
  int e = (b << CSH) + t;
  if (e < N_E) {
    float z = z_l[t];
    zM[e] = z;
    q = z * wn[e].y;
  }
  red[t] = q;
  __syncthreads();
  for (int o = 256; o > 0; o >>= 1) {
    if (t < o) red[t] += red[t + o];
    __syncthreads();
  }
  if (t == 0) atomicAdd(sumzn, red[0]);
}

// ---------------- fine D: Z2 in LDS + weighted X colsums -> tg[64] ----------------
__global__ __launch_bounds__(512) void k_fD(const unsigned* __restrict__ binnedR, const int* __restrict__ cntR,
                                            const float* __restrict__ zM,
                                            const float* __restrict__ X,
                                            const float* __restrict__ rdegf, const float* __restrict__ Wv,
                                            const float* __restrict__ Sv,
                                            float* __restrict__ tg) {
  __shared__ float Z_l[256];
  __shared__ float tl[64];
  int t = threadIdx.x, b = blockIdx.x;
  if (t < 256) Z_l[t] = 0.f;
  if (t >= 256 && t < 320) tl[t - 256] = 0.f;
  __syncthreads();
  int cnt = cntR[b];
  const unsigned* rec = binnedR + (size_t)b * CAPR;
  int p = t;
  for (; p + 1536 < cnt; p += 2048) {
    unsigned a0 = rec[p], a1 = rec[p + 512], a2 = rec[p + 1024], a3 = rec[p + 1536];
    float v0 = zM[a0 & VMASK], v1 = zM[a1 & VMASK], v2 = zM[a2 & VMASK], v3 = zM[a3 & VMASK];
    atomicAdd(&Z_l[a0 >> 18], v0); atomicAdd(&Z_l[a1 >> 18], v1);
    atomicAdd(&Z_l[a2 >> 18], v2); atomicAdd(&Z_l[a3 >> 18], v3);
  }
  for (; p < cnt; p += 512) {
    unsigned a0 = rec[p];
    atomicAdd(&Z_l[a0 >> 18], zM[a0 & VMASK]);
  }
  __syncthreads();
  // weighted X colsums: t0 += x, t1 += Wv*x, t2 += (deg+Sv)*x, t3 += (Wv+Z2)*x
  if (t < 256) {
    int lane = t & 63;
    int v = (b << RSH) + t;
    bool ok = v < N_V;
    float g0 = 0.f, g1 = 0.f, g2 = 0.f, g3 = 0.f;
    if (ok) {
      float W = Wv[v];
      g0 = 1.f; g1 = W;
      g2 = rdegf[v] + Sv[v];
      g3 = W + Z_l[t];
    }
    const float2* X2 = (const float2*)X;
#pragma unroll
    for (int q = 0; q < 7; q++) {
      float2 xp = ok ? X2[(size_t)v * 7 + q] : make_float2(0.f, 0.f);
#pragma unroll
      for (int hh = 0; hh < 2; hh++) {
        float xv = hh ? xp.y : xp.x;
        int d = 2 * q + hh;
        float v0 = xv * g0, v1 = xv * g1, v2 = xv * g2, v3 = xv * g3;
        v0 += __shfl_xor(v0, 1);  v0 += __shfl_xor(v0, 2);  v0 += __shfl_xor(v0, 4);
        v0 += __shfl_xor(v0, 8);  v0 += __shfl_xor(v0, 16); v0 += __shfl_xor(v0, 32);
        v1 += __shfl_xor(v1, 1);  v1 += __shfl_xor(v1, 2);  v1 += __shfl_xor(v1, 4);
        v1 += __shfl_xor(v1, 8);  v1 += __shfl_xor(v1, 16); v1 += __shfl_xor(v1, 32);
        v2 += __shfl_xor(v2, 1);  v2 += __shfl_xor(v2, 2);  v2 += __shfl_xor(v2, 4);
        v2 += __shfl_xor(v2, 8);  v2 += __shfl_xor(v2, 16); v2 += __shfl_xor(v2, 32);
        v3 += __shfl_xor(v3, 1);  v3 += __shfl_xor(v3, 2);  v3 += __shfl_xor(v3, 4);
        v3 += __shfl_xor(v3, 8);  v3 += __shfl_xor(v3, 16); v3 += __shfl_xor(v3, 32);
        if (lane == 0) {
          atomicAdd(&tl[d], v0);
          atomicAdd(&tl[16 + d], v1);
          atomicAdd(&tl[32 + d], v2);
          atomicAdd(&tl[48 + d], v3);
        }
      }
    }
  }
  __syncthreads();
  if (t < 64) atomicAdd(&tg[t], tl[t]);
}

// ---------------- final: expand cs = t@W0f + scalar*b0f, push Wl1, output heads ----------------
__global__ __launch_bounds__(128) void k_final(const float* __restrict__ tg,
                                               const float* __restrict__ qsum,
                                               const float* __restrict__ sumn2, const float* __restrict__ sumzn,
                                               const float* __restrict__ W0f, const float* __restrict__ b0f,
                                               const float* __restrict__ Wl1, const float* __restrict__ bl1,
                                               const float* __restrict__ Wo0, const float* __restrict__ bo0,
                                               const float* __restrict__ Wo1, const float* __restrict__ bo1,
                                               float* __restrict__ out) {
  __shared__ float cs[512];
  __shared__ float red[128];
  int t = threadIdx.x;
  float Q = qsum[0];
  {
    float c0 = 0.f, c1 = 0.f, c2 = 0.f, c3 = 0.f;
    for (int d = 0; d < D_IN; d++) {
      float w = W0f[d * H + t];
      c0 += tg[d] * w;
      c1 += tg[16 + d] * w;
      c2 += tg[32 + d] * w;
      c3 += tg[48 + d] * w;
    }
    float bv = b0f[t];
    cs[t]       = c0 + (float)N_V * bv;
    cs[128 + t] = c1 + Q * bv;
    cs[256 + t] = c2 + ((float)NNZ + sumn2[0]) * bv;
    cs[384 + t] = c3 + (Q + sumzn[0]) * bv;
  }
  __syncthreads();
  float sx = 0.f, se = 0.f;
  for (int k = 0; k < H; k++) {
    float wv = Wl1[k * H + t];
    float csx = cs[k] + cs[128 + k];          // colsum(a2) = colsum(h1) + sum w_k e1_k
    sx += (csx + cs[384 + k]) * wv;
    se += cs[256 + k] * wv;
  }
  sx += ((float)N_V + Q) * bl1[t];
  se += (float)NNZ * bl1[t];
  red[t] = sx * (1.f / (float)N_V) * Wo0[t] + se * (1.f / (float)N_E) * Wo1[t];
  __syncthreads();
  for (int o = 64; o > 0; o >>= 1) {
    if (t < o) red[t] += red[t + o];
    __syncthreads();
  }
  if (t == 0) out[0] = red[0] + bo0[0] + bo1[0];
}

extern "C" void kernel_launch(void* const* d_in, const int* in_sizes, int n_in,
                              void* d_out, int out_size, void* d_ws, size_t ws_size,
                              hipStream_t stream) {
  const float* x0in = (const float*)d_in[0];
  const int* rows   = (const int*)d_in[2];
  const int* cols   = (const int*)d_in[3];
  const float* W0   = (const float*)d_in[4];
  const float* b0   = (const float*)d_in[5];
  const float* Wl0  = (const float*)d_in[8];
  const float* bl0  = (const float*)d_in[9];
  const float* Wl1  = (const float*)d_in[10];
  const float* bl1  = (const float*)d_in[11];
  const float* Wo0  = (const float*)d_in[12];
  const float* bo0  = (const float*)d_in[13];
  const float* Wo1  = (const float*)d_in[14];
  const float* bo1  = (const float*)d_in[15];
  float* out = (float*)d_out;
  char* ws = (char*)d_ws;

  // ---- workspace layout (zero [0, 4608) only) ----
  int*    cntR  = (int*)(ws + 0);            // 391 ints (pad 2048)
  int*    cntC  = (int*)(ws + 2048);         // 391 ints (pad 2048)
  float*  qsum  = (float*)(ws + 4096);       // 4
  float*  sumn2 = (float*)(ws + 4100);       // 4
  float*  sumzn = (float*)(ws + 4104);       // 4
  float*  tg    = (float*)(ws + 4352);       // 64 floats -> memset [0, 4608)
  float*  rdegf = (float*)(ws + 8192);       // 400,000
  float*  invdg = (float*)(ws + 408192);     // 400,000
  float*  Wv    = (float*)(ws + 808192);     // 400,000
  float*  Sv    = (float*)(ws + 1208192);    // 400,000
  float*  WvD   = (float*)(ws + 1608192);    // 400,000
  float2* wn    = (float2*)(ws + 2008192);   // 1,600,000
  float*  zM    = (float*)(ws + 3608192);    // 800,000
  float*  W0f   = (float*)(ws + 4408192);    // 7,168
  float*  b0f   = (float*)(ws + 4415360);    // 512
  unsigned* binnedR = (unsigned*)(ws + 4415872);  // 391*3072*4 = 4,804,608
  unsigned* binnedC = (unsigned*)(ws + 9220480);  // 4,804,608
  // total: 14,025,088 B

  hipMemsetAsync(ws, 0, 4608, stream);
  k_bin2<<<dim3(NBIN + D_IN + 1), dim3(1024), 0, stream>>>(rows, cols, W0, b0, Wl0, bl0,
                                                           W0f, b0f, binnedR, cntR, binnedC, cntC);
  k_fhist<<<dim3(NB_R), dim3(512), 0, stream>>>(binnedR, cntR, rdegf, invdg);
  k_fA<<<dim3(NB_C), dim3(512), 0, stream>>>(binnedC, cntC, invdg, wn, qsum, sumn2);
  k_fB<<<dim3(NB_R), dim3(512), 0, stream>>>(binnedR, cntR, wn, invdg, Wv, Sv, WvD);
  k_fC<<<dim3(NB_C), dim3(512), 0, stream>>>(binnedC, cntC, WvD, wn, zM, sumzn);
  k_fD<<<dim3(NB_R), dim3(512), 0, stream>>>(binnedR, cntR, zM, x0in, rdegf, Wv, Sv, tg);
  k_final<<<dim3(1), dim3(128), 0, stream>>>(tg, qsum, sumn2, sumzn, W0f, b0f,
                                             Wl1, bl1, Wo0, bo0, Wo1, bo1, out);
}